// Round 7
// baseline (62.769 us; speedup 1.0000x reference)
//
#include <hip/hip_runtime.h>

typedef __attribute__((ext_vector_type(8))) short   bf16x8;
typedef __attribute__((ext_vector_type(4))) float   f32x4;
typedef __attribute__((ext_vector_type(4))) unsigned int u32x4;

#define HT 8           // output rows per block (main kernel)
#define XT_W 130       // padded pixel stride: col 0 and col 129 are zero

__device__ __forceinline__ unsigned short f2bf(float f) {
    union { float f; unsigned u; } v; v.f = f;
    unsigned u = v.u;
    u += 0x7FFFu + ((u >> 16) & 1u);   // RNE
    return (unsigned short)(u >> 16);
}

// ---------------------------------------------------------------------------
// Pre-pass: x (N=32, C=32, H=128, W=128) f32 NCHW -> x_t (N,H,130,32) bf16,
// c contiguous (64B per pixel), pixel index p = w+1, cols 0 & 129 zeroed.
// 4 h-rows per block, double-buffered LDS transpose, 1 barrier per row.
// ---------------------------------------------------------------------------
__global__ __launch_bounds__(256, 4)
void nchw_to_nhwc_bf16(const float* __restrict__ x, unsigned short* __restrict__ xt) {
    const int wh = blockIdx.x, hq = blockIdx.y, n = blockIdx.z;
    const int tid = threadIdx.x;
    const int cb = tid >> 6, w = tid & 63;       // c-octet, w within 64
    const int wg = wh * 64 + w;

    __shared__ u32x4 tile[2][64 * 5];            // [w][cb] padded stride 5

    const float* p0 = x + (((size_t)(n * 32 + cb * 8) * 128) * 128) + wg;
    u32x4* dst = (u32x4*)xt;

    #pragma unroll
    for (int i = 0; i < 4; ++i) {
        const int h = hq * 4 + i;
        const float* p = p0 + h * 128;
        float v[8];
        #pragma unroll
        for (int j = 0; j < 8; ++j) v[j] = p[j * 16384];
        u32x4 pk;
        pk[0] = (unsigned)f2bf(v[0]) | ((unsigned)f2bf(v[1]) << 16);
        pk[1] = (unsigned)f2bf(v[2]) | ((unsigned)f2bf(v[3]) << 16);
        pk[2] = (unsigned)f2bf(v[4]) | ((unsigned)f2bf(v[5]) << 16);
        pk[3] = (unsigned)f2bf(v[6]) | ((unsigned)f2bf(v[7]) << 16);
        tile[i & 1][w * 5 + cb] = pk;
        __syncthreads();
        // contiguous write: thread tid emits 16B for (pixel tid>>2, octet tid&3)
        const int base = ((n * 128 + h) * XT_W + 1 + wh * 64) * 4;
        dst[base + tid] = tile[i & 1][(tid >> 2) * 5 + (tid & 3)];
        // zero border columns (p=0 by wh==0 blocks, p=129 by wh==1)
        if (tid < 4) {
            const u32x4 z = {0u, 0u, 0u, 0u};
            const int col = (wh == 0) ? 0 : 129;
            dst[((n * 128 + h) * XT_W + col) * 4 + tid] = z;
        }
    }
}

// ---------------------------------------------------------------------------
// Main conv: zero LDS, zero barriers. Wave owns one 16-och tile of a
// (n, 8h x 64w) tile. Operand-swapped MFMA (A=pixels, B=weights) so D has
// row=pixel, col=och -> f32x4 stores of 4 consecutive w.
// ---------------------------------------------------------------------------
__global__ __launch_bounds__(256, 4)
void conv3x3_mfma(const unsigned short* __restrict__ xt,
                  const float* __restrict__ wk,
                  float* __restrict__ out) {
    const int hb = blockIdx.x, wh = blockIdx.y, n = blockIdx.z;
    const int H0 = hb * HT, W0 = wh * 64;
    const int lane = threadIdx.x & 63, wid = threadIdx.x >> 6;
    const int lq = lane >> 4, lr = lane & 15;

    // ---- weights -> registers (B operand): lane holds w_eff[och=wid*16+lr][c=lq*8+e]
    // Raw buffer index: ((c*3+ki)*3+kj)*64 + o   (reshape quirk).
    bf16x8 wB[9];
    #pragma unroll
    for (int p = 0; p < 9; ++p) {
        const int ki = p / 3, kj = p % 3;
        union { bf16x8 v; unsigned short s[8]; } u;
        #pragma unroll
        for (int j = 0; j < 8; ++j) {
            const int c = lq * 8 + j;
            u.s[j] = f2bf(wk[((c * 3 + ki) * 3 + kj) * 64 + wid * 16 + lr]);
        }
        wB[p] = u.v;
    }

    // ---- accumulators: 3-row ring x 4 pixel groups ----
    f32x4 acc[3][4];
    const f32x4 zero = {0.f, 0.f, 0.f, 0.f};
    #pragma unroll
    for (int a = 0; a < 3; ++a)
        #pragma unroll
        for (int pg = 0; pg < 4; ++pg) acc[a][pg] = zero;

    // per-thread output base (operand-swapped D): och = wid*16 + lr (col),
    // pixel = W0 + pg*16 + lq*4 + j (row) -> f32x4 over j.
    float* obase = out + ((size_t)(n * 64 + wid * 16 + lr) * 128) * 128 + W0 + lq * 4;

    // A-frag (pixels): lane holds x_t[pixel = W0+pg*16+lr+kj-1][c = lq*8..+7]
#define VOFF(PG, KJ) ((W0 + (PG) * 16 + lr + (KJ)) * 32 + lq * 8)

#define ROW(RHO)                                                              \
    {                                                                         \
        const int rg = H0 + (RHO) - 1;                                        \
        if ((unsigned)rg < 128u) {                                            \
            const unsigned short* rowp = xt + (size_t)(n * 128 + rg) * (XT_W * 32); \
            _Pragma("unroll")                                                 \
            for (int pg = 0; pg < 4; ++pg) {                                  \
                const bf16x8 fb0 = *(const bf16x8*)(rowp + VOFF(pg, 0));      \
                const bf16x8 fb1 = *(const bf16x8*)(rowp + VOFF(pg, 1));      \
                const bf16x8 fb2 = *(const bf16x8*)(rowp + VOFF(pg, 2));      \
                _Pragma("unroll")                                             \
                for (int ki = 0; ki < 3; ++ki) {                              \
                    if ((RHO) - ki < 0 || (RHO) - ki > HT - 1) continue;      \
                    const int a = ((RHO) - ki + 1) % 3;                       \
                    acc[a][pg] = __builtin_amdgcn_mfma_f32_16x16x32_bf16(     \
                        fb0, wB[ki * 3 + 0], acc[a][pg], 0, 0, 0);            \
                    acc[a][pg] = __builtin_amdgcn_mfma_f32_16x16x32_bf16(     \
                        fb1, wB[ki * 3 + 1], acc[a][pg], 0, 0, 0);            \
                    acc[a][pg] = __builtin_amdgcn_mfma_f32_16x16x32_bf16(     \
                        fb2, wB[ki * 3 + 2], acc[a][pg], 0, 0, 0);            \
                }                                                             \
            }                                                                 \
        }                                                                     \
        if ((RHO) >= 2) {                                                     \
            const int h = H0 + (RHO) - 2;                                     \
            const int a = ((RHO) - 1) % 3;                                    \
            _Pragma("unroll")                                                 \
            for (int pg = 0; pg < 4; ++pg) {                                  \
                *(f32x4*)(obase + h * 128 + pg * 16) = acc[a][pg];            \
                acc[a][pg] = zero;                                            \
            }                                                                 \
        }                                                                     \
    }

    ROW(0) ROW(1) ROW(2) ROW(3) ROW(4) ROW(5) ROW(6) ROW(7) ROW(8) ROW(9)
#undef ROW
#undef VOFF
}

extern "C" void kernel_launch(void* const* d_in, const int* in_sizes, int n_in,
                              void* d_out, int out_size, void* d_ws, size_t ws_size,
                              hipStream_t stream) {
    const float* x  = (const float*)d_in[0];
    const float* wk = (const float*)d_in[1];
    float* out = (float*)d_out;
    unsigned short* xt = (unsigned short*)d_ws;   // 32*128*130*32 bf16 = 34 MiB

    {   // pre-pass: NCHW f32 -> padded NHWC bf16 (+ zeroed border cols)
        dim3 grid(2, 32, 32);    // wh, h-quad, n  -> 2048 blocks
        nchw_to_nhwc_bf16<<<grid, dim3(256), 0, stream>>>(x, xt);
    }
    {   // main conv
        dim3 grid(16, 2, 32);    // hb, wh, n  -> 1024 blocks = 4 per CU
        conv3x3_mfma<<<grid, dim3(256), 0, stream>>>(xt, wk, out);
    }
}